// Round 1
// baseline (727.205 us; speedup 1.0000x reference)
//
#include <hip/hip_runtime.h>
#include <math.h>

typedef __bf16 bf16;
typedef __bf16 bf16x8 __attribute__((ext_vector_type(8)));
typedef __bf16 bf16x4 __attribute__((ext_vector_type(4)));
typedef __bf16 bf16x2 __attribute__((ext_vector_type(2)));
typedef float f32x4 __attribute__((ext_vector_type(4)));

#define ROWS 16384   // B*T

// ---- direct global->LDS 16B DMA (gfx950). LDS dest = wave-uniform base + lane*16.
typedef __attribute__((address_space(3))) void* lds_vp;
typedef const __attribute__((address_space(1))) void* glb_vp;
__device__ __forceinline__ void gload16(const void* g, void* l) {
  __builtin_amdgcn_global_load_lds((glb_vp)g, (lds_vp)l, 16, 0, 0);
}

// ---------------- 0. cast f32 -> bf16 (weights) ----------------
__global__ __launch_bounds__(256) void cast_kernel(
    const float* __restrict__ src, bf16* __restrict__ dst, int n)
{
  int i = (blockIdx.x * 256 + threadIdx.x) * 8;
  if (i >= n) return;
  float4 a = *(const float4*)(src + i);
  float4 b = *(const float4*)(src + i + 4);
  bf16x8 o;
  o[0] = (bf16)a.x; o[1] = (bf16)a.y; o[2] = (bf16)a.z; o[3] = (bf16)a.w;
  o[4] = (bf16)b.x; o[5] = (bf16)b.y; o[6] = (bf16)b.z; o[7] = (bf16)b.w;
  *(bf16x8*)(dst + i) = o;
}

// ---------------- 1. x = frame_features + sinusoidal PE ----------------
__global__ __launch_bounds__(256) void pe_add_kernel(
    const float* __restrict__ ff, const int* __restrict__ idx, bf16* __restrict__ x)
{
  int p   = blockIdx.x * 256 + threadIdx.x;   // over ROWS*512 sin/cos pairs
  int row = p >> 9;
  int j   = p & 511;
  float pos = (float)idx[row];
  float d2  = (float)(2 * j) * (1.0f / 1024.0f);
  float dv  = expf(-9.210340371976184f * d2);   // 10000^(-2j/D)
  float ang = pos * dv;
  float s, c;
  sincosf(ang, &s, &c);
  int base = row * 1024 + 2 * j;
  float2 f = *(const float2*)(ff + base);
  bf16x2 o;
  o[0] = (bf16)(f.x + s);
  o[1] = (bf16)(f.y + c);
  *(bf16x2*)(x + base) = o;
}

// ---------------- 2. 256x256 8-phase GEMM: C = A[M,K] * Bw[N,K]^T + bias ----
// Plain-HIP port of the HK/learn_hip m201 schedule (T2 st_16x32 swizzle +
// T3/T4 8-phase counted-vmcnt + T5 setprio). 8 waves (2M x 4N), BK=64,
// 128 KiB LDS double-buffered. Per-wave output 128x64 (acc[8][4] f32x4).
//
// Race-free staging protocol (derived; one vmcnt checkpoint per K-tile):
//   phases per K-tile m (buf b = m&1):
//     P1: read A[0:4]x2ks + B[0:2]x2ks (12 ds_read_b128); stage B-h0(m+1)->!b
//     P2: read A[4:8]x2ks (8);                             stage B-h1(m+1)->!b
//     P3: read B[2:4]x2ks (4);                             stage A-h0(m+2)-> b
//     P4: (0 reads);                                       stage A-h1(m+2)-> b
//     checkpoint: vmcnt(4) (vmcnt(0) entering last K-tile), barrier.
//   Overwrite-safety: A-half reads complete in P1/P2 (regs held to P4),
//   overwrite issued P3/P4 (barrier between). B-half reads P1/P3, overwrite
//   issued P1/P2 of the NEXT K-tile. Completion: at checkpoint, only the
//   newest 2 half-tiles (4 loads) may be in flight = A-halves of kt m+2.
//
// LDS layout per matrix: [buf][rg=row/16][ks=kcol/32] subtiles of 1024 B
// (16 rows x 32 bf16). st_16x32 swizzle: elem_off ^= ((row>>3)&1)<<4.
// global_load_lds writes linearly, so the SOURCE lane is pre-swizzled:
// le = lane ^ (((lane>>5)&1)<<1)  (same involution, 32 B granularity).
#define MFMA16 __builtin_amdgcn_mfma_f32_16x16x32_bf16
#define SB  __builtin_amdgcn_sched_barrier(0)
#define BAR asm volatile("s_barrier" ::: "memory")

template<bool GELU, bool RES>
__global__ __launch_bounds__(512, 2) void gemm8(
    const bf16* __restrict__ A, const bf16* __restrict__ Bw,
    const float* __restrict__ bias, const bf16* __restrict__ resid,
    bf16* __restrict__ C, int M, int N, int K)
{
  extern __shared__ char smem[];       // 131072 B: lA 64 KB | lB 64 KB
  bf16* lA = (bf16*)smem;
  bf16* lB = (bf16*)(smem + 65536);

  const int tid  = threadIdx.x;
  const int wave = tid >> 6;
  const int lane = tid & 63;
  const int wm = wave >> 2, wn = wave & 3;   // 2 x 4 wave grid
  const int ln = lane & 15, q = lane >> 4;
  const int wm8 = wm * 8, wn4 = wn * 4;
  // swizzled frag-read offset within a subtile column (elem units)
  const int rsw = (ln * 32 + q * 8) ^ (((ln >> 3) & 1) << 4);

  // XCD-aware block swizzle (all grids here are % 8 == 0), M-major in-chunk
  const int nwg = gridDim.x;
  const int nbm = M >> 8;
  const int swz = (blockIdx.x & 7) * (nwg >> 3) + (blockIdx.x >> 3);
  const int bm = (swz % nbm) << 8;
  const int bn = (swz / nbm) << 8;

  // staging source (pre-swizzled lane)
  const int le = lane ^ (((lane >> 5) & 1) << 1);
  const int sr = le >> 2;              // row within 16-row group
  const int sc = (le & 3) * 8;         // k-col within 32-col subtile
  const bf16* gA = A  + (size_t)(bm + wave * 16 + sr) * K + sc;
  const bf16* gB = Bw + (size_t)(bn + wave * 16 + sr) * K + sc;
  const size_t hstep = (size_t)128 * K;   // M-half row step

#define STAGE_A(h, bb, kk) do { \
    bf16* _d = lA + (bb) * 16384 + ((h) * 8 + wave) * 1024; \
    gload16(gA + (size_t)(h) * hstep + (kk), _d); \
    gload16(gA + (size_t)(h) * hstep + (kk) + 32, _d + 512); } while (0)
#define STAGE_B(h, bb, kk) do { \
    bf16* _d = lB + (bb) * 16384 + ((h) * 8 + wave) * 1024; \
    gload16(gB + (size_t)(h) * hstep + (kk), _d); \
    gload16(gB + (size_t)(h) * hstep + (kk) + 32, _d + 512); } while (0)
#define LDA8(dst, t, ks, bb) (dst) = *(const bf16x8*)(lA + (bb) * 16384 + (wm8 + (t)) * 1024 + (ks) * 512 + rsw)
#define LDB8(dst, n, ks, bb) (dst) = *(const bf16x8*)(lB + (bb) * 16384 + (wn4 + (n)) * 1024 + (ks) * 512 + rsw)

  f32x4 acc[8][4];
#pragma unroll
  for (int i = 0; i < 8; i++)
#pragma unroll
    for (int j = 0; j < 4; j++) acc[i][j] = {0.f, 0.f, 0.f, 0.f};

  const int nkt = K >> 6;

  // ---- prologue: kt0 {A-h0,A-h1,B-h0,B-h1}, kt1 {A-h0,A-h1} (issue = need order)
  STAGE_A(0, 0, 0);  STAGE_A(1, 0, 0);
  STAGE_B(0, 0, 0);  STAGE_B(1, 0, 0);
  STAGE_A(0, 1, 64); STAGE_A(1, 1, 64);
  SB; asm volatile("s_waitcnt vmcnt(4)" ::: "memory"); SB;
  BAR; SB;

  bf16x8 alo[4][2], ahi[4][2], bq[2][2];

  for (int m = 0; m < nkt; ++m) {
    const int b  = m & 1;
    const int k0 = m << 6;

    // -------- P1: A[0:4], B[0:2]; stage B-h0(m+1)
#pragma unroll
    for (int t = 0; t < 4; t++) { LDA8(alo[t][0], t, 0, b); LDA8(alo[t][1], t, 1, b); }
    LDB8(bq[0][0], 0, 0, b); LDB8(bq[0][1], 0, 1, b);
    LDB8(bq[1][0], 1, 0, b); LDB8(bq[1][1], 1, 1, b);
    if (m + 1 < nkt) STAGE_B(0, b ^ 1, k0 + 64);
    SB; BAR; SB;
    __builtin_amdgcn_s_setprio(1);
#pragma unroll
    for (int t = 0; t < 4; t++)
#pragma unroll
      for (int n = 0; n < 2; n++) {
        acc[t][n] = MFMA16(alo[t][0], bq[n][0], acc[t][n], 0, 0, 0);
        acc[t][n] = MFMA16(alo[t][1], bq[n][1], acc[t][n], 0, 0, 0);
      }
    __builtin_amdgcn_s_setprio(0);
    SB; BAR; SB;

    // -------- P2: A[4:8]; stage B-h1(m+1)
#pragma unroll
    for (int t = 0; t < 4; t++) { LDA8(ahi[t][0], t + 4, 0, b); LDA8(ahi[t][1], t + 4, 1, b); }
    if (m + 1 < nkt) STAGE_B(1, b ^ 1, k0 + 64);
    SB; BAR; SB;
    __builtin_amdgcn_s_setprio(1);
#pragma unroll
    for (int t = 0; t < 4; t++)
#pragma unroll
      for (int n = 0; n < 2; n++) {
        acc[t + 4][n] = MFMA16(ahi[t][0], bq[n][0], acc[t + 4][n], 0, 0, 0);
        acc[t + 4][n] = MFMA16(ahi[t][1], bq[n][1], acc[t + 4][n], 0, 0, 0);
      }
    __builtin_amdgcn_s_setprio(0);
    SB; BAR; SB;

    // -------- P3: B[2:4]; stage A-h0(m+2)
    LDB8(bq[0][0], 2, 0, b); LDB8(bq[0][1], 2, 1, b);
    LDB8(bq[1][0], 3, 0, b); LDB8(bq[1][1], 3, 1, b);
    if (m + 2 < nkt) STAGE_A(0, b, k0 + 128);
    SB; BAR; SB;
    __builtin_amdgcn_s_setprio(1);
#pragma unroll
    for (int t = 0; t < 4; t++)
#pragma unroll
      for (int n = 0; n < 2; n++) {
        acc[t][n + 2] = MFMA16(alo[t][0], bq[n][0], acc[t][n + 2], 0, 0, 0);
        acc[t][n + 2] = MFMA16(alo[t][1], bq[n][1], acc[t][n + 2], 0, 0, 0);
      }
    __builtin_amdgcn_s_setprio(0);
    SB; BAR; SB;

    // -------- P4: stage A-h1(m+2); checkpoint
    if (m + 2 < nkt) STAGE_A(1, b, k0 + 128);
    SB; BAR; SB;
    __builtin_amdgcn_s_setprio(1);
#pragma unroll
    for (int t = 0; t < 4; t++)
#pragma unroll
      for (int n = 0; n < 2; n++) {
        acc[t + 4][n + 2] = MFMA16(ahi[t][0], bq[n][0], acc[t + 4][n + 2], 0, 0, 0);
        acc[t + 4][n + 2] = MFMA16(ahi[t][1], bq[n][1], acc[t + 4][n + 2], 0, 0, 0);
      }
    __builtin_amdgcn_s_setprio(0);
    SB;
    if (m == nkt - 2)     { asm volatile("s_waitcnt vmcnt(0)" ::: "memory"); }
    else if (m < nkt - 2) { asm volatile("s_waitcnt vmcnt(4)" ::: "memory"); }
    SB; BAR; SB;
  }

  // ---- epilogue: 8 passes over tm. C/D layout col=ln, row=q*4+reg.
  // LDS repack 32x256 (stride 264), coalesced read-back, resid/GELU, 2x16B store.
  float bv[4];
#pragma unroll
  for (int tn = 0; tn < 4; tn++) bv[tn] = bias[bn + wn * 64 + tn * 16 + ln];
  bf16* eb = (bf16*)smem;
  const int lrow = tid >> 4;          // 0..31
  const int cb   = (tid & 15) * 16;   // 0..240
#pragma unroll
  for (int tm = 0; tm < 8; tm++) {
    __syncthreads();
#pragma unroll
    for (int tn = 0; tn < 4; tn++)
#pragma unroll
      for (int i = 0; i < 4; i++)
        eb[(wm * 16 + q * 4 + i) * 264 + wn * 64 + tn * 16 + ln] =
            (bf16)(acc[tm][tn][i] + bv[tn]);
    __syncthreads();
    int gR = bm + (lrow >> 4) * 128 + tm * 16 + (lrow & 15);
    size_t rowoff = (size_t)gR * N + bn + cb;
    bf16x8 v0 = *(const bf16x8*)&eb[lrow * 264 + cb];
    bf16x8 v1 = *(const bf16x8*)&eb[lrow * 264 + cb + 8];
    if (RES) {
      bf16x8 r0 = *(const bf16x8*)(resid + rowoff);
      bf16x8 r1 = *(const bf16x8*)(resid + rowoff + 8);
#pragma unroll
      for (int u = 0; u < 8; u++) {
        v0[u] = (bf16)((float)v0[u] + (float)r0[u]);
        v1[u] = (bf16)((float)v1[u] + (float)r1[u]);
      }
    }
    if (GELU) {
#pragma unroll
      for (int u = 0; u < 8; u++) {
        float a = (float)v0[u], c = (float)v1[u];
        v0[u] = (bf16)(0.5f * a * (1.0f + erff(a * 0.70710678118654752f)));
        v1[u] = (bf16)(0.5f * c * (1.0f + erff(c * 0.70710678118654752f)));
      }
    }
    *(bf16x8*)(C + rowoff)     = v0;
    *(bf16x8*)(C + rowoff + 8) = v1;
  }
#undef STAGE_A
#undef STAGE_B
#undef LDA8
#undef LDB8
}

// ---------------- 3. windowed attention: one block per (window, head) ----------
__global__ __launch_bounds__(256) void attn_kernel(
    const bf16* __restrict__ qkv, bf16* __restrict__ o)
{
  __shared__ float sq[16][132], sk[16][132], sv[16][132];
  __shared__ float ss[16][17];

  int wid = blockIdx.x;
  int h   = wid & 7;
  int win = wid >> 3;
  int tb  = win * 16;     // token base row

  int t  = threadIdx.x;
  int r  = t >> 4;        // 0..15
  int c8 = (t & 15) * 8;  // 0..120

  const bf16* base = qkv + (size_t)(tb + r) * 3072 + c8;
  bf16x8 qv = *(const bf16x8*)(base + h * 128);
  bf16x8 kv = *(const bf16x8*)(base + 1024 + h * 128);
  bf16x8 vv = *(const bf16x8*)(base + 2048 + h * 128);
#pragma unroll
  for (int u = 0; u < 8; u++) {
    sq[r][c8 + u] = (float)qv[u];
    sk[r][c8 + u] = (float)kv[u];
    sv[r][c8 + u] = (float)vv[u];
  }
  __syncthreads();

  {  // scores: thread (i,j) does 128-dot
    int i = t >> 4, jj = t & 15;
    float s = 0.f;
#pragma unroll 8
    for (int d = 0; d < 128; d++) s += sq[i][d] * sk[jj][d];
    ss[i][jj] = s * 0.08838834764831845f;   // 1/sqrt(128)
  }
  __syncthreads();

  if (t < 16) {  // softmax, one thread per row
    float m = -1e30f;
    for (int jj = 0; jj < 16; jj++) m = fmaxf(m, ss[t][jj]);
    float sum = 0.f;
    for (int jj = 0; jj < 16; jj++) { float e = expf(ss[t][jj] - m); ss[t][jj] = e; sum += e; }
    float inv = 1.0f / sum;
    for (int jj = 0; jj < 16; jj++) ss[t][jj] *= inv;
  }
  __syncthreads();

  {  // o = attn @ v : thread does 8 output elems
    int i = t >> 4; int d0 = (t & 15) * 8;
    float acc[8] = {0, 0, 0, 0, 0, 0, 0, 0};
#pragma unroll
    for (int jj = 0; jj < 16; jj++) {
      float a = ss[i][jj];
#pragma unroll
      for (int u = 0; u < 8; u++) acc[u] += a * sv[jj][d0 + u];
    }
    bf16* op = o + (size_t)(tb + i) * 1024 + h * 128 + d0;
#pragma unroll
    for (int u = 0; u < 8; u++) op[u] = (bf16)acc[u];
  }
}

// ---------------- 4. LayerNorm (row = 1024, biased var), templated output ------
template<typename OUT_T>
__global__ __launch_bounds__(256) void ln_kernel(
    const bf16* __restrict__ x, const float* __restrict__ g,
    const float* __restrict__ b, OUT_T* __restrict__ y)
{
  __shared__ float red[8];
  int row = blockIdx.x;
  int t   = threadIdx.x;
  int lane = t & 63, wave = t >> 6;

  bf16x4 v4 = *(const bf16x4*)(x + (size_t)row * 1024 + t * 4);
  float v[4];
  float s = 0.f, sq = 0.f;
#pragma unroll
  for (int u = 0; u < 4; u++) {
    v[u] = (float)v4[u];
    s += v[u];
    sq += v[u] * v[u];
  }
  for (int off = 32; off > 0; off >>= 1) {
    s  += __shfl_down(s, off);
    sq += __shfl_down(sq, off);
  }
  if (lane == 0) { red[wave * 2] = s; red[wave * 2 + 1] = sq; }
  __syncthreads();
  float st = red[0] + red[2] + red[4] + red[6];
  float qt = red[1] + red[3] + red[5] + red[7];
  float mean = st * (1.0f / 1024.0f);
  float var  = qt * (1.0f / 1024.0f) - mean * mean;
  float inv  = rsqrtf(var + 1e-5f);
  int c = t * 4;
  OUT_T* yr = y + (size_t)row * 1024 + c;
#pragma unroll
  for (int u = 0; u < 4; u++)
    yr[u] = (OUT_T)((v[u] - mean) * inv * g[c + u] + b[c + u]);
}

// ---------------- launch ----------------
extern "C" void kernel_launch(void* const* d_in, const int* in_sizes, int n_in,
                              void* d_out, int out_size, void* d_ws, size_t ws_size,
                              hipStream_t stream) {
  const float* ff    = (const float*)d_in[0];
  const int*   idx   = (const int*)d_in[1];
  const float* w_qkv = (const float*)d_in[2];
  const float* b_qkv = (const float*)d_in[3];
  const float* w_out = (const float*)d_in[4];
  const float* b_out = (const float*)d_in[5];
  const float* w1    = (const float*)d_in[6];
  const float* b1    = (const float*)d_in[7];
  const float* w2    = (const float*)d_in[8];
  const float* b2    = (const float*)d_in[9];
  const float* g1    = (const float*)d_in[10];
  const float* be1   = (const float*)d_in[11];
  const float* g2    = (const float*)d_in[12];
  const float* be2   = (const float*)d_in[13];
  float* out = (float*)d_out;

  // opt-in to 128 KiB dynamic LDS (once)
  static bool attrs_done = false;
  if (!attrs_done) {
    attrs_done = true;
    hipFuncSetAttribute(reinterpret_cast<const void*>(&gemm8<false, false>),
                        hipFuncAttributeMaxDynamicSharedMemorySize, 131072);
    hipFuncSetAttribute(reinterpret_cast<const void*>(&gemm8<false, true>),
                        hipFuncAttributeMaxDynamicSharedMemorySize, 131072);
    hipFuncSetAttribute(reinterpret_cast<const void*>(&gemm8<true, false>),
                        hipFuncAttributeMaxDynamicSharedMemorySize, 131072);
  }

  char* p = (char*)d_ws;
  bf16* x_bf = (bf16*)p;  p += (size_t)ROWS * 1024 * 2;   // 32MB
  bf16* big  = (bf16*)p;  p += (size_t)ROWS * 4096 * 2;   // 128MB: qkv|o, later gelu acts
  bf16* s_bf = (bf16*)p;  p += (size_t)ROWS * 1024 * 2;   // 32MB
  bf16* h_bf = (bf16*)p;  p += (size_t)ROWS * 1024 * 2;   // 32MB
  bf16* wqb  = (bf16*)p;  p += (size_t)3072 * 1024 * 2;
  bf16* wob  = (bf16*)p;  p += (size_t)1024 * 1024 * 2;
  bf16* w1b  = (bf16*)p;  p += (size_t)4096 * 1024 * 2;
  bf16* w2b  = (bf16*)p;  p += (size_t)1024 * 4096 * 2;
  bf16* o_bf = big + (size_t)ROWS * 3072;   // lives in big's tail during attention
  bf16* g_bf = big;                          // reuses big after attention done

  cast_kernel<<<3072 * 1024 / 8 / 256, 256, 0, stream>>>(w_qkv, wqb, 3072 * 1024);
  cast_kernel<<<1024 * 1024 / 8 / 256, 256, 0, stream>>>(w_out, wob, 1024 * 1024);
  cast_kernel<<<4096 * 1024 / 8 / 256, 256, 0, stream>>>(w1, w1b, 4096 * 1024);
  cast_kernel<<<1024 * 4096 / 8 / 256, 256, 0, stream>>>(w2, w2b, 1024 * 4096);

  pe_add_kernel<<<ROWS * 512 / 256, 256, 0, stream>>>(ff, idx, x_bf);

  // grids: (M/256) * (N/256); all % 8 == 0 for the XCD swizzle
  gemm8<false, false><<<64 * 12, 512, 131072, stream>>>(
      x_bf, wqb, b_qkv, nullptr, big, ROWS, 3072, 1024);
  attn_kernel<<<(ROWS / 16) * 8, 256, 0, stream>>>(big, o_bf);
  gemm8<false, true><<<64 * 4, 512, 131072, stream>>>(
      o_bf, wob, b_out, x_bf, s_bf, ROWS, 1024, 1024);
  ln_kernel<bf16><<<ROWS, 256, 0, stream>>>(s_bf, g1, be1, h_bf);
  gemm8<true, false><<<64 * 16, 512, 131072, stream>>>(
      h_bf, w1b, b1, nullptr, big, ROWS, 4096, 1024);
  gemm8<false, true><<<64 * 4, 512, 131072, stream>>>(
      g_bf, w2b, b2, h_bf, s_bf, ROWS, 1024, 4096);
  ln_kernel<float><<<ROWS, 256, 0, stream>>>(s_bf, g2, be2, out);
}

// Round 2
// 671.097 us; speedup vs baseline: 1.0836x; 1.0836x over previous
//
#include <hip/hip_runtime.h>
#include <math.h>

typedef __bf16 bf16;
typedef __bf16 bf16x8 __attribute__((ext_vector_type(8)));
typedef __bf16 bf16x4 __attribute__((ext_vector_type(4)));
typedef __bf16 bf16x2 __attribute__((ext_vector_type(2)));
typedef float f32x4 __attribute__((ext_vector_type(4)));

#define ROWS 16384   // B*T

// ---- direct global->LDS 16B DMA (gfx950). LDS dest = wave-uniform base + lane*16.
typedef __attribute__((address_space(3))) void* lds_vp;
typedef const __attribute__((address_space(1))) void* glb_vp;
__device__ __forceinline__ void gload16(const void* g, void* l) {
  __builtin_amdgcn_global_load_lds((glb_vp)g, (lds_vp)l, 16, 0, 0);
}

// ---------------- 0. cast f32 -> bf16 (weights) ----------------
__global__ __launch_bounds__(256) void cast_kernel(
    const float* __restrict__ src, bf16* __restrict__ dst, int n)
{
  int i = (blockIdx.x * 256 + threadIdx.x) * 8;
  if (i >= n) return;
  float4 a = *(const float4*)(src + i);
  float4 b = *(const float4*)(src + i + 4);
  bf16x8 o;
  o[0] = (bf16)a.x; o[1] = (bf16)a.y; o[2] = (bf16)a.z; o[3] = (bf16)a.w;
  o[4] = (bf16)b.x; o[5] = (bf16)b.y; o[6] = (bf16)b.z; o[7] = (bf16)b.w;
  *(bf16x8*)(dst + i) = o;
}

// ---------------- 1. x = frame_features + sinusoidal PE ----------------
__global__ __launch_bounds__(256) void pe_add_kernel(
    const float* __restrict__ ff, const int* __restrict__ idx, bf16* __restrict__ x)
{
  int p   = blockIdx.x * 256 + threadIdx.x;   // over ROWS*512 sin/cos pairs
  int row = p >> 9;
  int j   = p & 511;
  float pos = (float)idx[row];
  float d2  = (float)(2 * j) * (1.0f / 1024.0f);
  float dv  = expf(-9.210340371976184f * d2);   // 10000^(-2j/D)
  float ang = pos * dv;
  float s, c;
  sincosf(ang, &s, &c);
  int base = row * 1024 + 2 * j;
  float2 f = *(const float2*)(ff + base);
  bf16x2 o;
  o[0] = (bf16)(f.x + s);
  o[1] = (bf16)(f.y + c);
  *(bf16x2*)(x + base) = o;
}

// ---------------- 2. 256x256 8-phase GEMM: C = A[M,K] * Bw[N,K]^T + bias ----
// m201 schedule, template-literal this time: __builtin_amdgcn_s_barrier()
// (NOT raw asm with "memory" clobber -> that forced vmcnt drains, round-1
// post-mortem), explicit lgkmcnt(0)+sched_barrier(0) per rule #18, counted
// vmcnt only at K-tile boundaries.
//
// Race-free staging protocol (one vmcnt checkpoint per K-tile, verified):
//   P1: read A[0:4]+B[0:2] (12 ds_read_b128); stage B-h0(m+1)->!b ; MFMA q00
//   P2: read A[4:8]         (8);              stage B-h1(m+1)->!b ; MFMA q10
//   P3: read B[2:4]         (4);              stage A-h0(m+2)-> b ; MFMA q01
//   P4:                                        stage A-h1(m+2)-> b ; MFMA q11
//   checkpoint: vmcnt(4) (vmcnt(0) entering last K-tile), barrier.
//   Entering kt j, exactly A(j+1)'s 4 loads are in flight; all of kt j's
//   data is vmcnt-confirmed.  Overwrite-issue always follows (barrier-
//   separated) the lgkmcnt(0) that drained the last reads of that region.
//
// LDS: [buf][rg=row/16][ks=kcol/32] 1024-B subtiles (16 rows x 32 bf16),
// st_16x32 swizzle elem_off ^= ((row>>3)&1)<<4; gload_lds writes linearly so
// the global SOURCE lane is pre-swizzled with the same involution.
#define MFMA16 __builtin_amdgcn_mfma_f32_16x16x32_bf16
#define SB  __builtin_amdgcn_sched_barrier(0)

template<bool GELU, bool RES>
__global__ __launch_bounds__(512, 2) void gemm8(
    const bf16* __restrict__ A, const bf16* __restrict__ Bw,
    const float* __restrict__ bias, const bf16* __restrict__ resid,
    bf16* __restrict__ C, int M, int N, int K)
{
  extern __shared__ char smem[];       // 131072 B: lA 64 KB | lB 64 KB
  bf16* lA = (bf16*)smem;
  bf16* lB = (bf16*)(smem + 65536);

  const int tid  = threadIdx.x;
  const int wave = tid >> 6;
  const int lane = tid & 63;
  const int wm = wave >> 2, wn = wave & 3;   // 2 x 4 wave grid
  const int ln = lane & 15, q = lane >> 4;
  const int wm8 = wm * 8, wn4 = wn * 4;
  // swizzled frag-read offset within a subtile (elem units)
  const int rsw = (ln * 32 + q * 8) ^ (((ln >> 3) & 1) << 4);

  // XCD-aware block swizzle, bn-FASTEST within each XCD chunk:
  // A (big activation) stripe per chunk = 8 rows x 256 x K*2B ~= 4MB -> L2-fits,
  // B (weights, <=8MB) streams from L3. Round-1 M-fastest refetched A ~8x.
  const int nwg = gridDim.x;
  const int nbn = N >> 8;
  const int swz = (blockIdx.x & 7) * (nwg >> 3) + (blockIdx.x >> 3);
  const int bm = (swz / nbn) << 8;
  const int bn = (swz % nbn) << 8;

  // staging source (pre-swizzled lane)
  const int le = lane ^ (((lane >> 5) & 1) << 1);
  const int sr = le >> 2;              // row within 16-row group
  const int sc = (le & 3) * 8;         // k-col within 32-col subtile
  const bf16* gA = A  + (size_t)(bm + wave * 16 + sr) * K + sc;
  const bf16* gB = Bw + (size_t)(bn + wave * 16 + sr) * K + sc;
  const size_t hstep = (size_t)128 * K;   // M-half row step

#define STAGE_A(h, bb, kk) do { \
    bf16* _d = lA + (bb) * 16384 + ((h) * 8 + wave) * 1024; \
    gload16(gA + (size_t)(h) * hstep + (kk), _d); \
    gload16(gA + (size_t)(h) * hstep + (kk) + 32, _d + 512); } while (0)
#define STAGE_B(h, bb, kk) do { \
    bf16* _d = lB + (bb) * 16384 + ((h) * 8 + wave) * 1024; \
    gload16(gB + (size_t)(h) * hstep + (kk), _d); \
    gload16(gB + (size_t)(h) * hstep + (kk) + 32, _d + 512); } while (0)
#define LDA8(dst, t, ks, bb) (dst) = *(const bf16x8*)(lA + (bb) * 16384 + (wm8 + (t)) * 1024 + (ks) * 512 + rsw)
#define LDB8(dst, n, ks, bb) (dst) = *(const bf16x8*)(lB + (bb) * 16384 + (wn4 + (n)) * 1024 + (ks) * 512 + rsw)

  f32x4 acc[8][4];
#pragma unroll
  for (int i = 0; i < 8; i++)
#pragma unroll
    for (int j = 0; j < 4; j++) acc[i][j] = {0.f, 0.f, 0.f, 0.f};

  const int nkt = K >> 6;

  // ---- prologue: kt0 {A,B complete}, kt1 {A halves} in flight
  STAGE_A(0, 0, 0);  STAGE_A(1, 0, 0);
  STAGE_B(0, 0, 0);  STAGE_B(1, 0, 0);
  STAGE_A(0, 1, 64); STAGE_A(1, 1, 64);
  SB; asm volatile("s_waitcnt vmcnt(4)"); SB;
  __builtin_amdgcn_s_barrier();

  bf16x8 alo[4][2], ahi[4][2], bq[2][2];

  for (int m = 0; m < nkt; ++m) {
    const int b  = m & 1;
    const int k0 = m << 6;

    // -------- P1: A[0:4], B[0:2]; stage B-h0(m+1); MFMA quadrant (lo, n01)
#pragma unroll
    for (int t = 0; t < 4; t++) { LDA8(alo[t][0], t, 0, b); LDA8(alo[t][1], t, 1, b); }
    LDB8(bq[0][0], 0, 0, b); LDB8(bq[0][1], 0, 1, b);
    LDB8(bq[1][0], 1, 0, b); LDB8(bq[1][1], 1, 1, b);
    if (m + 1 < nkt) STAGE_B(0, b ^ 1, k0 + 64);
    __builtin_amdgcn_s_barrier();
    asm volatile("s_waitcnt lgkmcnt(0)");
    SB;
    __builtin_amdgcn_s_setprio(1);
#pragma unroll
    for (int t = 0; t < 4; t++)
#pragma unroll
      for (int n = 0; n < 2; n++) {
        acc[t][n] = MFMA16(alo[t][0], bq[n][0], acc[t][n], 0, 0, 0);
        acc[t][n] = MFMA16(alo[t][1], bq[n][1], acc[t][n], 0, 0, 0);
      }
    __builtin_amdgcn_s_setprio(0);
    __builtin_amdgcn_s_barrier();

    // -------- P2: A[4:8]; stage B-h1(m+1); MFMA quadrant (hi, n01)
#pragma unroll
    for (int t = 0; t < 4; t++) { LDA8(ahi[t][0], t + 4, 0, b); LDA8(ahi[t][1], t + 4, 1, b); }
    if (m + 1 < nkt) STAGE_B(1, b ^ 1, k0 + 64);
    __builtin_amdgcn_s_barrier();
    asm volatile("s_waitcnt lgkmcnt(0)");
    SB;
    __builtin_amdgcn_s_setprio(1);
#pragma unroll
    for (int t = 0; t < 4; t++)
#pragma unroll
      for (int n = 0; n < 2; n++) {
        acc[t + 4][n] = MFMA16(ahi[t][0], bq[n][0], acc[t + 4][n], 0, 0, 0);
        acc[t + 4][n] = MFMA16(ahi[t][1], bq[n][1], acc[t + 4][n], 0, 0, 0);
      }
    __builtin_amdgcn_s_setprio(0);
    __builtin_amdgcn_s_barrier();

    // -------- P3: B[2:4]; stage A-h0(m+2); MFMA quadrant (lo, n23)
    LDB8(bq[0][0], 2, 0, b); LDB8(bq[0][1], 2, 1, b);
    LDB8(bq[1][0], 3, 0, b); LDB8(bq[1][1], 3, 1, b);
    if (m + 2 < nkt) STAGE_A(0, b, k0 + 128);
    __builtin_amdgcn_s_barrier();
    asm volatile("s_waitcnt lgkmcnt(0)");
    SB;
    __builtin_amdgcn_s_setprio(1);
#pragma unroll
    for (int t = 0; t < 4; t++)
#pragma unroll
      for (int n = 0; n < 2; n++) {
        acc[t][n + 2] = MFMA16(alo[t][0], bq[n][0], acc[t][n + 2], 0, 0, 0);
        acc[t][n + 2] = MFMA16(alo[t][1], bq[n][1], acc[t][n + 2], 0, 0, 0);
      }
    __builtin_amdgcn_s_setprio(0);
    __builtin_amdgcn_s_barrier();

    // -------- P4: stage A-h1(m+2); MFMA quadrant (hi, n23); checkpoint
    if (m + 2 < nkt) STAGE_A(1, b, k0 + 128);
    __builtin_amdgcn_s_barrier();
    __builtin_amdgcn_s_setprio(1);
#pragma unroll
    for (int t = 0; t < 4; t++)
#pragma unroll
      for (int n = 0; n < 2; n++) {
        acc[t + 4][n + 2] = MFMA16(ahi[t][0], bq[n][0], acc[t + 4][n + 2], 0, 0, 0);
        acc[t + 4][n + 2] = MFMA16(ahi[t][1], bq[n][1], acc[t + 4][n + 2], 0, 0, 0);
      }
    __builtin_amdgcn_s_setprio(0);
    SB;
    if (m == nkt - 2)     { asm volatile("s_waitcnt vmcnt(0)"); }
    else if (m < nkt - 2) { asm volatile("s_waitcnt vmcnt(4)"); }
    SB;
    __builtin_amdgcn_s_barrier();
  }

  // ---- epilogue: 8 passes over tm. C/D layout col=ln, row=q*4+reg.
  // LDS repack 32x256 (stride 264), coalesced read-back, resid/GELU, 2x16B store.
  float bv[4];
#pragma unroll
  for (int tn = 0; tn < 4; tn++) bv[tn] = bias[bn + wn * 64 + tn * 16 + ln];
  bf16* eb = (bf16*)smem;
  const int lrow = tid >> 4;          // 0..31
  const int cb   = (tid & 15) * 16;   // 0..240
#pragma unroll
  for (int tm = 0; tm < 8; tm++) {
    __syncthreads();
#pragma unroll
    for (int tn = 0; tn < 4; tn++)
#pragma unroll
      for (int i = 0; i < 4; i++)
        eb[(wm * 16 + q * 4 + i) * 264 + wn * 64 + tn * 16 + ln] =
            (bf16)(acc[tm][tn][i] + bv[tn]);
    __syncthreads();
    int gR = bm + (lrow >> 4) * 128 + tm * 16 + (lrow & 15);
    size_t rowoff = (size_t)gR * N + bn + cb;
    bf16x8 v0 = *(const bf16x8*)&eb[lrow * 264 + cb];
    bf16x8 v1 = *(const bf16x8*)&eb[lrow * 264 + cb + 8];
    if (RES) {
      bf16x8 r0 = *(const bf16x8*)(resid + rowoff);
      bf16x8 r1 = *(const bf16x8*)(resid + rowoff + 8);
#pragma unroll
      for (int u = 0; u < 8; u++) {
        v0[u] = (bf16)((float)v0[u] + (float)r0[u]);
        v1[u] = (bf16)((float)v1[u] + (float)r1[u]);
      }
    }
    if (GELU) {
      // tanh-form GELU, NaN-safe: a - a/(1+exp(2g)); ~9 VALU vs ~45 for erff.
      // 2.3022082 = 2*log2(e)*0.7978845608
#pragma unroll
      for (int u = 0; u < 8; u++) {
        float a = (float)v0[u], c = (float)v1[u];
        float ea = __builtin_amdgcn_exp2f(2.3022082f * a * (1.0f + 0.044715f * a * a));
        float ec = __builtin_amdgcn_exp2f(2.3022082f * c * (1.0f + 0.044715f * c * c));
        v0[u] = (bf16)(a - a * __builtin_amdgcn_rcpf(ea + 1.0f));
        v1[u] = (bf16)(c - c * __builtin_amdgcn_rcpf(ec + 1.0f));
      }
    }
    *(bf16x8*)(C + rowoff)     = v0;
    *(bf16x8*)(C + rowoff + 8) = v1;
  }
#undef STAGE_A
#undef STAGE_B
#undef LDA8
#undef LDB8
}

// ---------------- 3. windowed attention: one block per (window, head) ----------
__global__ __launch_bounds__(256) void attn_kernel(
    const bf16* __restrict__ qkv, bf16* __restrict__ o)
{
  __shared__ float sq[16][132], sk[16][132], sv[16][132];
  __shared__ float ss[16][17];

  int wid = blockIdx.x;
  int h   = wid & 7;
  int win = wid >> 3;
  int tb  = win * 16;     // token base row

  int t  = threadIdx.x;
  int r  = t >> 4;        // 0..15
  int c8 = (t & 15) * 8;  // 0..120

  const bf16* base = qkv + (size_t)(tb + r) * 3072 + c8;
  bf16x8 qv = *(const bf16x8*)(base + h * 128);
  bf16x8 kv = *(const bf16x8*)(base + 1024 + h * 128);
  bf16x8 vv = *(const bf16x8*)(base + 2048 + h * 128);
#pragma unroll
  for (int u = 0; u < 8; u++) {
    sq[r][c8 + u] = (float)qv[u];
    sk[r][c8 + u] = (float)kv[u];
    sv[r][c8 + u] = (float)vv[u];
  }
  __syncthreads();

  {  // scores: thread (i,j) does 128-dot
    int i = t >> 4, jj = t & 15;
    float s = 0.f;
#pragma unroll 8
    for (int d = 0; d < 128; d++) s += sq[i][d] * sk[jj][d];
    ss[i][jj] = s * 0.08838834764831845f;   // 1/sqrt(128)
  }
  __syncthreads();

  if (t < 16) {  // softmax, one thread per row
    float m = -1e30f;
    for (int jj = 0; jj < 16; jj++) m = fmaxf(m, ss[t][jj]);
    float sum = 0.f;
    for (int jj = 0; jj < 16; jj++) { float e = expf(ss[t][jj] - m); ss[t][jj] = e; sum += e; }
    float inv = 1.0f / sum;
    for (int jj = 0; jj < 16; jj++) ss[t][jj] *= inv;
  }
  __syncthreads();

  {  // o = attn @ v : thread does 8 output elems
    int i = t >> 4; int d0 = (t & 15) * 8;
    float acc[8] = {0, 0, 0, 0, 0, 0, 0, 0};
#pragma unroll
    for (int jj = 0; jj < 16; jj++) {
      float a = ss[i][jj];
#pragma unroll
      for (int u = 0; u < 8; u++) acc[u] += a * sv[jj][d0 + u];
    }
    bf16* op = o + (size_t)(tb + i) * 1024 + h * 128 + d0;
#pragma unroll
    for (int u = 0; u < 8; u++) op[u] = (bf16)acc[u];
  }
}

// ---------------- 4. LayerNorm (row = 1024, biased var), templated output ------
template<typename OUT_T>
__global__ __launch_bounds__(256) void ln_kernel(
    const bf16* __restrict__ x, const float* __restrict__ g,
    const float* __restrict__ b, OUT_T* __restrict__ y)
{
  __shared__ float red[8];
  int row = blockIdx.x;
  int t   = threadIdx.x;
  int lane = t & 63, wave = t >> 6;

  bf16x4 v4 = *(const bf16x4*)(x + (size_t)row * 1024 + t * 4);
  float v[4];
  float s = 0.f, sq = 0.f;
#pragma unroll
  for (int u = 0; u < 4; u++) {
    v[u] = (float)v4[u];
    s += v[u];
    sq += v[u] * v[u];
  }
  for (int off = 32; off > 0; off >>= 1) {
    s  += __shfl_down(s, off);
    sq += __shfl_down(sq, off);
  }
  if (lane == 0) { red[wave * 2] = s; red[wave * 2 + 1] = sq; }
  __syncthreads();
  float st = red[0] + red[2] + red[4] + red[6];
  float qt = red[1] + red[3] + red[5] + red[7];
  float mean = st * (1.0f / 1024.0f);
  float var  = qt * (1.0f / 1024.0f) - mean * mean;
  float inv  = rsqrtf(var + 1e-5f);
  int c = t * 4;
  OUT_T* yr = y + (size_t)row * 1024 + c;
#pragma unroll
  for (int u = 0; u < 4; u++)
    yr[u] = (OUT_T)((v[u] - mean) * inv * g[c + u] + b[c + u]);
}

// ---------------- launch ----------------
extern "C" void kernel_launch(void* const* d_in, const int* in_sizes, int n_in,
                              void* d_out, int out_size, void* d_ws, size_t ws_size,
                              hipStream_t stream) {
  const float* ff    = (const float*)d_in[0];
  const int*   idx   = (const int*)d_in[1];
  const float* w_qkv = (const float*)d_in[2];
  const float* b_qkv = (const float*)d_in[3];
  const float* w_out = (const float*)d_in[4];
  const float* b_out = (const float*)d_in[5];
  const float* w1    = (const float*)d_in[6];
  const float* b1    = (const float*)d_in[7];
  const float* w2    = (const float*)d_in[8];
  const float* b2    = (const float*)d_in[9];
  const float* g1    = (const float*)d_in[10];
  const float* be1   = (const float*)d_in[11];
  const float* g2    = (const float*)d_in[12];
  const float* be2   = (const float*)d_in[13];
  float* out = (float*)d_out;

  // opt-in to 128 KiB dynamic LDS (once)
  static bool attrs_done = false;
  if (!attrs_done) {
    attrs_done = true;
    hipFuncSetAttribute(reinterpret_cast<const void*>(&gemm8<false, false>),
                        hipFuncAttributeMaxDynamicSharedMemorySize, 131072);
    hipFuncSetAttribute(reinterpret_cast<const void*>(&gemm8<false, true>),
                        hipFuncAttributeMaxDynamicSharedMemorySize, 131072);
    hipFuncSetAttribute(reinterpret_cast<const void*>(&gemm8<true, false>),
                        hipFuncAttributeMaxDynamicSharedMemorySize, 131072);
  }

  char* p = (char*)d_ws;
  bf16* x_bf = (bf16*)p;  p += (size_t)ROWS * 1024 * 2;   // 32MB
  bf16* big  = (bf16*)p;  p += (size_t)ROWS * 4096 * 2;   // 128MB: qkv|o, later gelu acts
  bf16* s_bf = (bf16*)p;  p += (size_t)ROWS * 1024 * 2;   // 32MB
  bf16* h_bf = (bf16*)p;  p += (size_t)ROWS * 1024 * 2;   // 32MB
  bf16* wqb  = (bf16*)p;  p += (size_t)3072 * 1024 * 2;
  bf16* wob  = (bf16*)p;  p += (size_t)1024 * 1024 * 2;
  bf16* w1b  = (bf16*)p;  p += (size_t)4096 * 1024 * 2;
  bf16* w2b  = (bf16*)p;  p += (size_t)1024 * 4096 * 2;
  bf16* o_bf = big + (size_t)ROWS * 3072;   // lives in big's tail during attention
  bf16* g_bf = big;                          // reuses big after attention done

  cast_kernel<<<3072 * 1024 / 8 / 256, 256, 0, stream>>>(w_qkv, wqb, 3072 * 1024);
  cast_kernel<<<1024 * 1024 / 8 / 256, 256, 0, stream>>>(w_out, wob, 1024 * 1024);
  cast_kernel<<<4096 * 1024 / 8 / 256, 256, 0, stream>>>(w1, w1b, 4096 * 1024);
  cast_kernel<<<1024 * 4096 / 8 / 256, 256, 0, stream>>>(w2, w2b, 1024 * 4096);

  pe_add_kernel<<<ROWS * 512 / 256, 256, 0, stream>>>(ff, idx, x_bf);

  // grids: (M/256) * (N/256); all % 8 == 0 for the XCD swizzle
  gemm8<false, false><<<64 * 12, 512, 131072, stream>>>(
      x_bf, wqb, b_qkv, nullptr, big, ROWS, 3072, 1024);
  attn_kernel<<<(ROWS / 16) * 8, 256, 0, stream>>>(big, o_bf);
  gemm8<false, true><<<64 * 4, 512, 131072, stream>>>(
      o_bf, wob, b_out, x_bf, s_bf, ROWS, 1024, 1024);
  ln_kernel<bf16><<<ROWS, 256, 0, stream>>>(s_bf, g1, be1, h_bf);
  gemm8<true, false><<<64 * 16, 512, 131072, stream>>>(
      h_bf, w1b, b1, nullptr, big, ROWS, 4096, 1024);
  gemm8<false, true><<<64 * 4, 512, 131072, stream>>>(
      g_bf, w2b, b2, h_bf, s_bf, ROWS, 1024, 4096);
  ln_kernel<float><<<ROWS, 256, 0, stream>>>(s_bf, g2, be2, out);
}

// Round 3
// 663.953 us; speedup vs baseline: 1.0953x; 1.0108x over previous
//
#include <hip/hip_runtime.h>
#include <math.h>

typedef __bf16 bf16;
typedef __bf16 bf16x8 __attribute__((ext_vector_type(8)));
typedef __bf16 bf16x4 __attribute__((ext_vector_type(4)));
typedef __bf16 bf16x2 __attribute__((ext_vector_type(2)));
typedef float f32x4 __attribute__((ext_vector_type(4)));

#define ROWS 16384   // B*T

// ---- direct global->LDS 16B DMA (gfx950). LDS dest = wave-uniform base + lane*16.
typedef __attribute__((address_space(3))) void* lds_vp;
typedef const __attribute__((address_space(1))) void* glb_vp;
__device__ __forceinline__ void gload16(const void* g, void* l) {
  __builtin_amdgcn_global_load_lds((glb_vp)g, (lds_vp)l, 16, 0, 0);
}

// ---------------- 0. cast f32 -> bf16 (weights) ----------------
__global__ __launch_bounds__(256) void cast_kernel(
    const float* __restrict__ src, bf16* __restrict__ dst, int n)
{
  int i = (blockIdx.x * 256 + threadIdx.x) * 8;
  if (i >= n) return;
  float4 a = *(const float4*)(src + i);
  float4 b = *(const float4*)(src + i + 4);
  bf16x8 o;
  o[0] = (bf16)a.x; o[1] = (bf16)a.y; o[2] = (bf16)a.z; o[3] = (bf16)a.w;
  o[4] = (bf16)b.x; o[5] = (bf16)b.y; o[6] = (bf16)b.z; o[7] = (bf16)b.w;
  *(bf16x8*)(dst + i) = o;
}

// ---------------- 1. x = frame_features + sinusoidal PE ----------------
__global__ __launch_bounds__(256) void pe_add_kernel(
    const float* __restrict__ ff, const int* __restrict__ idx, bf16* __restrict__ x)
{
  int p   = blockIdx.x * 256 + threadIdx.x;   // over ROWS*512 sin/cos pairs
  int row = p >> 9;
  int j   = p & 511;
  float pos = (float)idx[row];
  float d2  = (float)(2 * j) * (1.0f / 1024.0f);
  float dv  = expf(-9.210340371976184f * d2);   // 10000^(-2j/D)
  float ang = pos * dv;
  float s, c;
  sincosf(ang, &s, &c);
  int base = row * 1024 + 2 * j;
  float2 f = *(const float2*)(ff + base);
  bf16x2 o;
  o[0] = (bf16)(f.x + s);
  o[1] = (bf16)(f.y + c);
  *(bf16x2*)(x + base) = o;
}

// ---------------- 2. 256x256 8-phase GEMM: C = A[M,K] * Bw[N,K]^T + bias ----
// Round-3 loop structure (T3 min-recipe form):
//   - STAGE issued FIRST in each phase (before ds_reads) -> max prefetch lead
//   - ONE barrier per phase (at phase start); no mid-phase lgkmcnt(0) drain:
//     compiler emits fine-grained lgkmcnt(N) per consuming MFMA, and
//     global_load_lds's may-alias LDS-write pins ds_read/stage ordering
//     intra-wave; the per-phase barrier gives inter-wave separation.
//   - counted vmcnt(4) once per K-tile at end of P4 (vmcnt(0) at nkt-2).
// Region safety: A-halves last read P1/P2, overwritten (issue) at P3/P4 start;
// B-halves last read P3, overwritten at next-tile P1/P2 start; >=1 barrier
// between last consuming-MFMA's lgkm-wait and the overwriting stage issue.
#define MFMA16 __builtin_amdgcn_mfma_f32_16x16x32_bf16

template<bool GELU, bool RES>
__global__ __launch_bounds__(512, 2) void gemm8(
    const bf16* __restrict__ A, const bf16* __restrict__ Bw,
    const float* __restrict__ bias, const bf16* __restrict__ resid,
    bf16* __restrict__ C, int M, int N, int K)
{
  extern __shared__ char smem[];       // 131072 B: lA 64 KB | lB 64 KB
  bf16* lA = (bf16*)smem;
  bf16* lB = (bf16*)(smem + 65536);

  const int tid  = threadIdx.x;
  const int wave = tid >> 6;
  const int lane = tid & 63;
  const int wm = wave >> 2, wn = wave & 3;   // 2 x 4 wave grid
  const int ln = lane & 15, q = lane >> 4;
  const int wm8 = wm * 8, wn4 = wn * 4;
  // swizzled frag-read offset within a subtile (elem units)
  const int rsw = (ln * 32 + q * 8) ^ (((ln >> 3) & 1) << 4);

  // XCD-aware block swizzle, bn-fastest within each XCD chunk:
  // per-XCD A-stripe ~4MB (L2-fits), B weights stream from L3.
  const int nwg = gridDim.x;
  const int nbn = N >> 8;
  const int swz = (blockIdx.x & 7) * (nwg >> 3) + (blockIdx.x >> 3);
  const int bm = (swz / nbn) << 8;
  const int bn = (swz % nbn) << 8;

  // staging source (pre-swizzled lane; involution matches read-side XOR)
  const int le = lane ^ (((lane >> 5) & 1) << 1);
  const int sr = le >> 2;              // row within 16-row group
  const int sc = (le & 3) * 8;         // k-col within 32-col subtile
  const bf16* gA = A  + (size_t)(bm + wave * 16 + sr) * K + sc;
  const bf16* gB = Bw + (size_t)(bn + wave * 16 + sr) * K + sc;
  const size_t hstep = (size_t)128 * K;   // M-half row step

#define STAGE_A(h, bb, kk) do { \
    bf16* _d = lA + (bb) * 16384 + ((h) * 8 + wave) * 1024; \
    gload16(gA + (size_t)(h) * hstep + (kk), _d); \
    gload16(gA + (size_t)(h) * hstep + (kk) + 32, _d + 512); } while (0)
#define STAGE_B(h, bb, kk) do { \
    bf16* _d = lB + (bb) * 16384 + ((h) * 8 + wave) * 1024; \
    gload16(gB + (size_t)(h) * hstep + (kk), _d); \
    gload16(gB + (size_t)(h) * hstep + (kk) + 32, _d + 512); } while (0)
#define LDA8(dst, t, ks, bb) (dst) = *(const bf16x8*)(lA + (bb) * 16384 + (wm8 + (t)) * 1024 + (ks) * 512 + rsw)
#define LDB8(dst, n, ks, bb) (dst) = *(const bf16x8*)(lB + (bb) * 16384 + (wn4 + (n)) * 1024 + (ks) * 512 + rsw)

  f32x4 acc[8][4];
#pragma unroll
  for (int i = 0; i < 8; i++)
#pragma unroll
    for (int j = 0; j < 4; j++) acc[i][j] = {0.f, 0.f, 0.f, 0.f};

  const int nkt = K >> 6;

  // ---- prologue: kt0 {A,B complete}, kt1 {A halves} in flight
  STAGE_A(0, 0, 0);  STAGE_A(1, 0, 0);
  STAGE_B(0, 0, 0);  STAGE_B(1, 0, 0);
  STAGE_A(0, 1, 64); STAGE_A(1, 1, 64);
  asm volatile("s_waitcnt vmcnt(4)");

  bf16x8 alo[4][2], ahi[4][2], bq[2][2];

  for (int m = 0; m < nkt; ++m) {
    const int b  = m & 1;
    const int k0 = m << 6;

    // -------- P1: stage B-h0(m+1); read A[0:4]+B[0:2]; MFMA (lo, n01)
    __builtin_amdgcn_s_barrier();
    if (m + 1 < nkt) STAGE_B(0, b ^ 1, k0 + 64);
#pragma unroll
    for (int t = 0; t < 4; t++) { LDA8(alo[t][0], t, 0, b); LDA8(alo[t][1], t, 1, b); }
    LDB8(bq[0][0], 0, 0, b); LDB8(bq[0][1], 0, 1, b);
    LDB8(bq[1][0], 1, 0, b); LDB8(bq[1][1], 1, 1, b);
    __builtin_amdgcn_s_setprio(1);
#pragma unroll
    for (int t = 0; t < 4; t++)
#pragma unroll
      for (int n = 0; n < 2; n++) {
        acc[t][n] = MFMA16(alo[t][0], bq[n][0], acc[t][n], 0, 0, 0);
        acc[t][n] = MFMA16(alo[t][1], bq[n][1], acc[t][n], 0, 0, 0);
      }
    __builtin_amdgcn_s_setprio(0);

    // -------- P2: stage B-h1(m+1); read A[4:8]; MFMA (hi, n01)
    __builtin_amdgcn_s_barrier();
    if (m + 1 < nkt) STAGE_B(1, b ^ 1, k0 + 64);
#pragma unroll
    for (int t = 0; t < 4; t++) { LDA8(ahi[t][0], t + 4, 0, b); LDA8(ahi[t][1], t + 4, 1, b); }
    __builtin_amdgcn_s_setprio(1);
#pragma unroll
    for (int t = 0; t < 4; t++)
#pragma unroll
      for (int n = 0; n < 2; n++) {
        acc[t + 4][n] = MFMA16(ahi[t][0], bq[n][0], acc[t + 4][n], 0, 0, 0);
        acc[t + 4][n] = MFMA16(ahi[t][1], bq[n][1], acc[t + 4][n], 0, 0, 0);
      }
    __builtin_amdgcn_s_setprio(0);

    // -------- P3: stage A-h0(m+2); read B[2:4]; MFMA (lo, n23)
    __builtin_amdgcn_s_barrier();
    if (m + 2 < nkt) STAGE_A(0, b, k0 + 128);
    LDB8(bq[0][0], 2, 0, b); LDB8(bq[0][1], 2, 1, b);
    LDB8(bq[1][0], 3, 0, b); LDB8(bq[1][1], 3, 1, b);
    __builtin_amdgcn_s_setprio(1);
#pragma unroll
    for (int t = 0; t < 4; t++)
#pragma unroll
      for (int n = 0; n < 2; n++) {
        acc[t][n + 2] = MFMA16(alo[t][0], bq[n][0], acc[t][n + 2], 0, 0, 0);
        acc[t][n + 2] = MFMA16(alo[t][1], bq[n][1], acc[t][n + 2], 0, 0, 0);
      }
    __builtin_amdgcn_s_setprio(0);

    // -------- P4: stage A-h1(m+2); MFMA (hi, n23); counted checkpoint
    __builtin_amdgcn_s_barrier();
    if (m + 2 < nkt) STAGE_A(1, b, k0 + 128);
    __builtin_amdgcn_s_setprio(1);
#pragma unroll
    for (int t = 0; t < 4; t++)
#pragma unroll
      for (int n = 0; n < 2; n++) {
        acc[t + 4][n + 2] = MFMA16(ahi[t][0], bq[n][0], acc[t + 4][n + 2], 0, 0, 0);
        acc[t + 4][n + 2] = MFMA16(ahi[t][1], bq[n][1], acc[t + 4][n + 2], 0, 0, 0);
      }
    __builtin_amdgcn_s_setprio(0);
    if (m == nkt - 2)     { asm volatile("s_waitcnt vmcnt(0)"); }
    else if (m < nkt - 2) { asm volatile("s_waitcnt vmcnt(4)"); }
  }

  // ---- epilogue: 8 passes over tm. C/D layout col=ln, row=q*4+reg.
  // LDS repack 32x256 (stride 264), coalesced read-back, resid/GELU, 2x16B store.
  float bv[4];
#pragma unroll
  for (int tn = 0; tn < 4; tn++) bv[tn] = bias[bn + wn * 64 + tn * 16 + ln];
  bf16* eb = (bf16*)smem;
  const int lrow = tid >> 4;          // 0..31
  const int cb   = (tid & 15) * 16;   // 0..240
#pragma unroll
  for (int tm = 0; tm < 8; tm++) {
    __syncthreads();
#pragma unroll
    for (int tn = 0; tn < 4; tn++)
#pragma unroll
      for (int i = 0; i < 4; i++)
        eb[(wm * 16 + q * 4 + i) * 264 + wn * 64 + tn * 16 + ln] =
            (bf16)(acc[tm][tn][i] + bv[tn]);
    __syncthreads();
    int gR = bm + (lrow >> 4) * 128 + tm * 16 + (lrow & 15);
    size_t rowoff = (size_t)gR * N + bn + cb;
    bf16x8 v0 = *(const bf16x8*)&eb[lrow * 264 + cb];
    bf16x8 v1 = *(const bf16x8*)&eb[lrow * 264 + cb + 8];
    if (RES) {
      bf16x8 r0 = *(const bf16x8*)(resid + rowoff);
      bf16x8 r1 = *(const bf16x8*)(resid + rowoff + 8);
#pragma unroll
      for (int u = 0; u < 8; u++) {
        v0[u] = (bf16)((float)v0[u] + (float)r0[u]);
        v1[u] = (bf16)((float)v1[u] + (float)r1[u]);
      }
    }
    if (GELU) {
      // tanh-form GELU, NaN-safe: a - a/(1+exp(2g)); ~9 VALU vs ~45 for erff.
#pragma unroll
      for (int u = 0; u < 8; u++) {
        float a = (float)v0[u], c = (float)v1[u];
        float ea = __builtin_amdgcn_exp2f(2.3022082f * a * (1.0f + 0.044715f * a * a));
        float ec = __builtin_amdgcn_exp2f(2.3022082f * c * (1.0f + 0.044715f * c * c));
        v0[u] = (bf16)(a - a * __builtin_amdgcn_rcpf(ea + 1.0f));
        v1[u] = (bf16)(c - c * __builtin_amdgcn_rcpf(ec + 1.0f));
      }
    }
    *(bf16x8*)(C + rowoff)     = v0;
    *(bf16x8*)(C + rowoff + 8) = v1;
  }
#undef STAGE_A
#undef STAGE_B
#undef LDA8
#undef LDB8
}

// ---------------- 3. windowed attention: one block per (window, head) ----------
__global__ __launch_bounds__(256) void attn_kernel(
    const bf16* __restrict__ qkv, bf16* __restrict__ o)
{
  __shared__ float sq[16][132], sk[16][132], sv[16][132];
  __shared__ float ss[16][17];

  int wid = blockIdx.x;
  int h   = wid & 7;
  int win = wid >> 3;
  int tb  = win * 16;     // token base row

  int t  = threadIdx.x;
  int r  = t >> 4;        // 0..15
  int c8 = (t & 15) * 8;  // 0..120

  const bf16* base = qkv + (size_t)(tb + r) * 3072 + c8;
  bf16x8 qv = *(const bf16x8*)(base + h * 128);
  bf16x8 kv = *(const bf16x8*)(base + 1024 + h * 128);
  bf16x8 vv = *(const bf16x8*)(base + 2048 + h * 128);
#pragma unroll
  for (int u = 0; u < 8; u++) {
    sq[r][c8 + u] = (float)qv[u];
    sk[r][c8 + u] = (float)kv[u];
    sv[r][c8 + u] = (float)vv[u];
  }
  __syncthreads();

  {  // scores: thread (i,j) does 128-dot
    int i = t >> 4, jj = t & 15;
    float s = 0.f;
#pragma unroll 8
    for (int d = 0; d < 128; d++) s += sq[i][d] * sk[jj][d];
    ss[i][jj] = s * 0.08838834764831845f;   // 1/sqrt(128)
  }
  __syncthreads();

  if (t < 16) {  // softmax, one thread per row
    float m = -1e30f;
    for (int jj = 0; jj < 16; jj++) m = fmaxf(m, ss[t][jj]);
    float sum = 0.f;
    for (int jj = 0; jj < 16; jj++) { float e = expf(ss[t][jj] - m); ss[t][jj] = e; sum += e; }
    float inv = 1.0f / sum;
    for (int jj = 0; jj < 16; jj++) ss[t][jj] *= inv;
  }
  __syncthreads();

  {  // o = attn @ v : thread does 8 output elems
    int i = t >> 4; int d0 = (t & 15) * 8;
    float acc[8] = {0, 0, 0, 0, 0, 0, 0, 0};
#pragma unroll
    for (int jj = 0; jj < 16; jj++) {
      float a = ss[i][jj];
#pragma unroll
      for (int u = 0; u < 8; u++) acc[u] += a * sv[jj][d0 + u];
    }
    bf16* op = o + (size_t)(tb + i) * 1024 + h * 128 + d0;
#pragma unroll
    for (int u = 0; u < 8; u++) op[u] = (bf16)acc[u];
  }
}

// ---------------- 4. LayerNorm (row = 1024, biased var), templated output ------
template<typename OUT_T>
__global__ __launch_bounds__(256) void ln_kernel(
    const bf16* __restrict__ x, const float* __restrict__ g,
    const float* __restrict__ b, OUT_T* __restrict__ y)
{
  __shared__ float red[8];
  int row = blockIdx.x;
  int t   = threadIdx.x;
  int lane = t & 63, wave = t >> 6;

  bf16x4 v4 = *(const bf16x4*)(x + (size_t)row * 1024 + t * 4);
  float v[4];
  float s = 0.f, sq = 0.f;
#pragma unroll
  for (int u = 0; u < 4; u++) {
    v[u] = (float)v4[u];
    s += v[u];
    sq += v[u] * v[u];
  }
  for (int off = 32; off > 0; off >>= 1) {
    s  += __shfl_down(s, off);
    sq += __shfl_down(sq, off);
  }
  if (lane == 0) { red[wave * 2] = s; red[wave * 2 + 1] = sq; }
  __syncthreads();
  float st = red[0] + red[2] + red[4] + red[6];
  float qt = red[1] + red[3] + red[5] + red[7];
  float mean = st * (1.0f / 1024.0f);
  float var  = qt * (1.0f / 1024.0f) - mean * mean;
  float inv  = rsqrtf(var + 1e-5f);
  int c = t * 4;
  OUT_T* yr = y + (size_t)row * 1024 + c;
#pragma unroll
  for (int u = 0; u < 4; u++)
    yr[u] = (OUT_T)((v[u] - mean) * inv * g[c + u] + b[c + u]);
}

// ---------------- launch ----------------
extern "C" void kernel_launch(void* const* d_in, const int* in_sizes, int n_in,
                              void* d_out, int out_size, void* d_ws, size_t ws_size,
                              hipStream_t stream) {
  const float* ff    = (const float*)d_in[0];
  const int*   idx   = (const int*)d_in[1];
  const float* w_qkv = (const float*)d_in[2];
  const float* b_qkv = (const float*)d_in[3];
  const float* w_out = (const float*)d_in[4];
  const float* b_out = (const float*)d_in[5];
  const float* w1    = (const float*)d_in[6];
  const float* b1    = (const float*)d_in[7];
  const float* w2    = (const float*)d_in[8];
  const float* b2    = (const float*)d_in[9];
  const float* g1    = (const float*)d_in[10];
  const float* be1   = (const float*)d_in[11];
  const float* g2    = (const float*)d_in[12];
  const float* be2   = (const float*)d_in[13];
  float* out = (float*)d_out;

  // opt-in to 128 KiB dynamic LDS (once)
  static bool attrs_done = false;
  if (!attrs_done) {
    attrs_done = true;
    hipFuncSetAttribute(reinterpret_cast<const void*>(&gemm8<false, false>),
                        hipFuncAttributeMaxDynamicSharedMemorySize, 131072);
    hipFuncSetAttribute(reinterpret_cast<const void*>(&gemm8<false, true>),
                        hipFuncAttributeMaxDynamicSharedMemorySize, 131072);
    hipFuncSetAttribute(reinterpret_cast<const void*>(&gemm8<true, false>),
                        hipFuncAttributeMaxDynamicSharedMemorySize, 131072);
  }

  char* p = (char*)d_ws;
  bf16* x_bf = (bf16*)p;  p += (size_t)ROWS * 1024 * 2;   // 32MB
  bf16* big  = (bf16*)p;  p += (size_t)ROWS * 4096 * 2;   // 128MB: qkv|o, later gelu acts
  bf16* s_bf = (bf16*)p;  p += (size_t)ROWS * 1024 * 2;   // 32MB
  bf16* h_bf = (bf16*)p;  p += (size_t)ROWS * 1024 * 2;   // 32MB
  bf16* wqb  = (bf16*)p;  p += (size_t)3072 * 1024 * 2;
  bf16* wob  = (bf16*)p;  p += (size_t)1024 * 1024 * 2;
  bf16* w1b  = (bf16*)p;  p += (size_t)4096 * 1024 * 2;
  bf16* w2b  = (bf16*)p;  p += (size_t)1024 * 4096 * 2;
  bf16* o_bf = big + (size_t)ROWS * 3072;   // lives in big's tail during attention
  bf16* g_bf = big;                          // reuses big after attention done

  cast_kernel<<<3072 * 1024 / 8 / 256, 256, 0, stream>>>(w_qkv, wqb, 3072 * 1024);
  cast_kernel<<<1024 * 1024 / 8 / 256, 256, 0, stream>>>(w_out, wob, 1024 * 1024);
  cast_kernel<<<4096 * 1024 / 8 / 256, 256, 0, stream>>>(w1, w1b, 4096 * 1024);
  cast_kernel<<<1024 * 4096 / 8 / 256, 256, 0, stream>>>(w2, w2b, 1024 * 4096);

  pe_add_kernel<<<ROWS * 512 / 256, 256, 0, stream>>>(ff, idx, x_bf);

  // grids: (M/256) * (N/256); all % 8 == 0 for the XCD swizzle
  gemm8<false, false><<<64 * 12, 512, 131072, stream>>>(
      x_bf, wqb, b_qkv, nullptr, big, ROWS, 3072, 1024);
  attn_kernel<<<(ROWS / 16) * 8, 256, 0, stream>>>(big, o_bf);
  gemm8<false, true><<<64 * 4, 512, 131072, stream>>>(
      o_bf, wob, b_out, x_bf, s_bf, ROWS, 1024, 1024);
  ln_kernel<bf16><<<ROWS, 256, 0, stream>>>(s_bf, g1, be1, h_bf);
  gemm8<true, false><<<64 * 16, 512, 131072, stream>>>(
      h_bf, w1b, b1, nullptr, big, ROWS, 4096, 1024);
  gemm8<false, true><<<64 * 4, 512, 131072, stream>>>(
      g_bf, w2b, b2, h_bf, s_bf, ROWS, 1024, 4096);
  ln_kernel<float><<<ROWS, 256, 0, stream>>>(s_bf, g2, be2, out);
}